// Round 7
// baseline (182.872 us; speedup 1.0000x reference)
//
#include <hip/hip_runtime.h>
#include <hip/hip_fp16.h>

#define HIDDEN 768
#define HEADS 12
#define HDIM 64
#define SEQ 2048
#define BATCH 4
#define ORDER 5
#define LOG2E 1.44269504088896f

typedef _Float16 f16;
typedef _Float16 f16x8 __attribute__((ext_vector_type(8)));
typedef _Float16 f16x4 __attribute__((ext_vector_type(4)));
typedef float f32x4 __attribute__((ext_vector_type(4)));

#define MFMA16x16x32(A, B, C) __builtin_amdgcn_mfma_f32_16x16x32_f16(A, B, C, 0, 0, 0)

#define GLD16(gptr, lptr)                                                     \
    __builtin_amdgcn_global_load_lds(                                         \
        (const __attribute__((address_space(1))) void*)(gptr),                \
        (__attribute__((address_space(3))) void*)(lptr), 16, 0, 0)

// ---------------------------------------------------------------------------
// Kernel 1: prep. (a) convert X -> Xh f16, Wq/Wk/Wv -> Wh[2304][768] f16;
// (b) Chebyshev bias table (x LOG2E).
// ---------------------------------------------------------------------------
#define NXG (8192 * 768 / 8)
#define NWG (768 * 768 / 8)
#define NCVT (NXG + 3 * NWG)
#define NBIAS (HEADS * (2 * SEQ - 1))

__global__ __launch_bounds__(256)
void prep_kernel(const float* __restrict__ X,
                 const float* __restrict__ Wq, const float* __restrict__ Wk,
                 const float* __restrict__ Wv, const float* __restrict__ alphas,
                 f16* __restrict__ Xh, f16* __restrict__ Wh,
                 float* __restrict__ biasTab)
{
    const int tid = blockIdx.x * 256 + threadIdx.x;
    if (tid < NCVT) {
        const float* src;
        f16* dst;
        size_t off;
        if (tid < NXG)               { src = X;  dst = Xh;              off = (size_t)tid * 8; }
        else if (tid < NXG + NWG)    { src = Wq; dst = Wh;              off = (size_t)(tid - NXG) * 8; }
        else if (tid < NXG + 2*NWG)  { src = Wk; dst = Wh + 768 * 768;  off = (size_t)(tid - NXG - NWG) * 8; }
        else                         { src = Wv; dst = Wh + 2*768*768;  off = (size_t)(tid - NXG - 2*NWG) * 8; }
        float4 a = *(const float4*)(src + off);
        float4 b = *(const float4*)(src + off + 4);
        f16x8 h;
        h[0] = (f16)a.x; h[1] = (f16)a.y; h[2] = (f16)a.z; h[3] = (f16)a.w;
        h[4] = (f16)b.x; h[5] = (f16)b.y; h[6] = (f16)b.z; h[7] = (f16)b.w;
        *(f16x8*)(dst + off) = h;
    } else {
        int idx = tid - NCVT;
        if (idx >= NBIAS) return;
        const int W = 2 * SEQ - 1;
        int h = idx / W;
        int t = idx - h * W;
        float x = (float)(t - (SEQ - 1)) / (float)(SEQ - 1);
        float tp = 1.0f;
        float tc = x;
        float acc = alphas[h * (ORDER + 1) + 0] * tp + alphas[h * (ORDER + 1) + 1] * tc;
#pragma unroll
        for (int k = 2; k <= ORDER; ++k) {
            float tn = 2.0f * x * tc - tp;
            acc += alphas[h * (ORDER + 1) + k] * tn;
            tp = tc; tc = tn;
        }
        biasTab[idx] = acc * LOG2E;
    }
}

// ---------------------------------------------------------------------------
// Kernel 2: fused QKV GEMM, m97 structure (global_load_lds w16, BK=32).
// ---------------------------------------------------------------------------
__global__ __launch_bounds__(256)
void qkv_kernel(const f16* __restrict__ Xh, const f16* __restrict__ Wh,
                const float* __restrict__ bq, const float* __restrict__ bk,
                const float* __restrict__ bv,
                f16* __restrict__ qf, f16* __restrict__ kf, f16* __restrict__ vtf)
{
    const int wgid = (blockIdx.x & 7) * 144 + (blockIdx.x >> 3);
    const int tileM = wgid / 18;
    const int tileN = wgid % 18;
    const int m0 = tileM * 128;
    const int n0g = tileN * 128;
    const int w = tileN / 6;
    const int nloc0 = n0g - w * 768;
    const float* __restrict__ bias = (w == 0) ? bq : (w == 1) ? bk : bv;

    __shared__ __align__(16) f16 sA[128][32];
    __shared__ __align__(16) f16 sB[128][32];

    const int t = threadIdx.x;
    const int lane = t & 63;
    const int wv = t >> 6;
    const int wm = wv >> 1, wn = wv & 1;
    const int fr = lane & 15;
    const int kg = lane >> 4;

    const int srow = lane >> 2;
    const int scol = (lane & 3) * 8;

    f32x4 acc[4][4];
#pragma unroll
    for (int i = 0; i < 4; ++i)
#pragma unroll
        for (int j = 0; j < 4; ++j) acc[i][j] = (f32x4)(0.0f);

    const f16* gA = Xh + (size_t)(m0 + wv * 32 + srow) * 768 + scol;
    const f16* gB = Wh + (size_t)(n0g + wv * 32 + srow) * 768 + scol;
    f16* lA0 = &sA[wv * 32][0];
    f16* lA1 = &sA[wv * 32 + 16][0];
    f16* lB0 = &sB[wv * 32][0];
    f16* lB1 = &sB[wv * 32 + 16][0];

    for (int kt = 0; kt < 768; kt += 32) {
        __syncthreads();
        GLD16(gA + kt, lA0);
        GLD16(gA + kt + 16 * 768, lA1);
        GLD16(gB + kt, lB0);
        GLD16(gB + kt + 16 * 768, lB1);
        __syncthreads();

        f16x8 af[4], bf[4];
#pragma unroll
        for (int i = 0; i < 4; ++i) {
            af[i] = *(const f16x8*)&sA[wm * 64 + i * 16 + fr][kg * 8];
            bf[i] = *(const f16x8*)&sB[wn * 64 + i * 16 + fr][kg * 8];
        }
#pragma unroll
        for (int mi = 0; mi < 4; ++mi)
#pragma unroll
            for (int ni = 0; ni < 4; ++ni)
                acc[mi][ni] = MFMA16x16x32(af[mi], bf[ni], acc[mi][ni]);
    }

    const int bb = m0 >> 11;
#pragma unroll
    for (int mi = 0; mi < 4; ++mi) {
        const int s0 = (m0 & 2047) + wm * 64 + mi * 16 + kg * 4;
#pragma unroll
        for (int ni = 0; ni < 4; ++ni) {
            const int nloc = nloc0 + wn * 64 + ni * 16 + fr;
            const int hh = nloc >> 6, d = nloc & 63;
            const size_t bh = (size_t)bb * HEADS + hh;
            const float bc = bias[nloc];
            if (w == 2) {
                f16x4 pv;
#pragma unroll
                for (int r = 0; r < 4; ++r) pv[r] = (f16)(acc[mi][ni][r] + bc);
                *(f16x4*)&vtf[(bh * HDIM + d) * SEQ + s0] = pv;
            } else if (w == 0) {
#pragma unroll
                for (int r = 0; r < 4; ++r)
                    qf[(bh * SEQ + s0 + r) * HDIM + d] =
                        (f16)((acc[mi][ni][r] + bc) * (0.125f * LOG2E));
            } else {
#pragma unroll
                for (int r = 0; r < 4; ++r)
                    kf[(bh * SEQ + s0 + r) * HDIM + d] = (f16)(acc[mi][ni][r] + bc);
            }
        }
    }
}

// ---------------------------------------------------------------------------
// Kernel 3: flash attention. XCD-affine grid; T14 reg-staged async staging
// (load next tile to regs BEFORE compute, ds_write AFTER barrier); single KV
// buffer; bias folded into MFMA C-init; 4 blocks/CU (LDS 39168 B).
// ---------------------------------------------------------------------------
__global__ __launch_bounds__(256, 4)
void attn_kernel(const f16* __restrict__ qf, const f16* __restrict__ kf,
                 const f16* __restrict__ vtf, const float* __restrict__ biasTab,
                 float* __restrict__ out)
{
    // XCD-affine: all 16 q-tiles of one (b,h) land on one XCD.
    const int xcd = blockIdx.x & 7;
    const int ii = blockIdx.x >> 3;
    const int qt = ii & 15;
    const int bh = (ii >> 4) * 8 + xcd;     // bijective
    const int h = bh % HEADS;
    const int b = bh / HEADS;
    const int q0 = qt * 128;

    __shared__ __align__(16) f16 sK[64][72];       // 9216 B
    __shared__ __align__(16) f16 sVT[64][72];      // 9216 B
    __shared__ __align__(16) f16 sPS[4][2048];     // per-wave P[32][64] swz, 16384 B
    __shared__ __align__(16) f16 sBiasH[2176];     // 4352 B

    const int t = threadIdx.x;
    const int lane = t & 63;
    const int wv = t >> 6;
    const int fr = lane & 15;
    const int kg = lane >> 4;
    const int r7 = fr & 7;

    // Stage bias slice as f16: sBiasH[u] = biasTab[h*4095 + u + 1920 - q0]
    {
        const float* bsrc = biasTab + (size_t)h * (2 * SEQ - 1) + 1920 - q0;
        for (int u = t; u < 2175; u += 256) sBiasH[u] = (f16)bsrc[u];
    }

    // Q fragments in registers (0.125*LOG2E folded in by qkv kernel)
    f16x8 aq[2][2];
#pragma unroll
    for (int s = 0; s < 2; ++s)
#pragma unroll
        for (int c = 0; c < 2; ++c)
            aq[s][c] = *(const f16x8*)(qf +
                ((size_t)bh * SEQ + q0 + wv * 32 + s * 16 + fr) * HDIM + c * 32 + kg * 8);

    f32x4 oacc[2][4];
    float lsum[2] = {0.0f, 0.0f};
#pragma unroll
    for (int s = 0; s < 2; ++s)
#pragma unroll
        for (int df = 0; df < 4; ++df) oacc[s][df] = (f32x4)(0.0f);

    // staging geometry: thread t covers row t>>2, col (t&3)*16 (halfs)
    const int srow = t >> 2;
    const int scol = (t & 3) * 16;
    const f16* const gkb = kf + ((size_t)bh * SEQ + srow) * HDIM + scol;
    const f16* const gvb = vtf + ((size_t)bh * HDIM + srow) * SEQ + scol;
    f16* const myP = &sPS[wv][0];

    f16x8 rk0, rk1, rv0, rv1;
    auto stage_load = [&](int j0) {
        rk0 = *(const f16x8*)(gkb + (size_t)j0 * HDIM);
        rk1 = *(const f16x8*)(gkb + (size_t)j0 * HDIM + 8);
        rv0 = *(const f16x8*)(gvb + j0);
        rv1 = *(const f16x8*)(gvb + j0 + 8);
    };
    auto stage_write = [&]() {
        *(f16x8*)&sK[srow][scol] = rk0;
        *(f16x8*)&sK[srow][scol + 8] = rk1;
        *(f16x8*)&sVT[srow][scol] = rv0;
        *(f16x8*)&sVT[srow][scol + 8] = rv1;
    };

    // prologue: tile 0 into LDS
    stage_load(0);
    stage_write();
    __syncthreads();   // kv + bias visible

    for (int j0 = 0; j0 < SEQ; j0 += 64) {
        const bool more = (j0 + 64 < SEQ);
        if (more) stage_load(j0 + 64);   // in flight during compute

        // bias (f16 -> f32): element (s,ni,r): key=j0+ni*16+kg*4+r, q=wv*32+s*16+fr
        const int ub = j0 + kg * 4 - wv * 32 - fr + 127;
        float bbv[5][4];
#pragma unroll
        for (int g = 0; g < 5; ++g)
#pragma unroll
            for (int r = 0; r < 4; ++r)
                bbv[g][r] = (float)sBiasH[ub + (g - 1) * 16 + r];

        // T[key][q] = K Q^T, accumulator initialized with the bias
        f32x4 tt[2][4];
#pragma unroll
        for (int s = 0; s < 2; ++s)
#pragma unroll
            for (int ni = 0; ni < 4; ++ni)
#pragma unroll
                for (int r = 0; r < 4; ++r) tt[s][ni][r] = bbv[ni - s + 1][r];
        __builtin_amdgcn_s_setprio(1);
#pragma unroll
        for (int ni = 0; ni < 4; ++ni) {
            const f16* kb = &sK[ni * 16 + fr][0];
            f16x8 bk0 = *(const f16x8*)(kb + kg * 8);
            f16x8 bk1 = *(const f16x8*)(kb + 32 + kg * 8);
            tt[0][ni] = MFMA16x16x32(bk0, aq[0][0], tt[0][ni]);
            tt[0][ni] = MFMA16x16x32(bk1, aq[0][1], tt[0][ni]);
            tt[1][ni] = MFMA16x16x32(bk0, aq[1][0], tt[1][ni]);
            tt[1][ni] = MFMA16x16x32(bk1, aq[1][1], tt[1][ni]);
        }
        __builtin_amdgcn_s_setprio(0);

        // softmax (no max subtraction) + P -> wave-private LDS (swizzled)
#pragma unroll
        for (int s = 0; s < 2; ++s) {
            float ls = 0.0f;
#pragma unroll
            for (int ni = 0; ni < 4; ++ni) {
                f16x4 ph;
#pragma unroll
                for (int r = 0; r < 4; ++r) {
                    float p = __builtin_amdgcn_exp2f(tt[s][ni][r]);
                    ls += p;
                    ph[r] = (f16)p;
                }
                *(f16x4*)(myP + (s * 16 + fr) * 64 +
                          (((ni * 2 + (kg >> 1)) ^ r7) * 8) + (kg & 1) * 4) = ph;
            }
            lsum[s] += ls;
        }

        // PV: O^T[d][q] += MFMA(VT rows, P rows)
        f16x8 ap00 = *(const f16x8*)(myP + fr * 64 + 8 * (kg ^ r7));
        f16x8 ap01 = *(const f16x8*)(myP + fr * 64 + 8 * ((kg + 4) ^ r7));
        f16x8 ap10 = *(const f16x8*)(myP + (16 + fr) * 64 + 8 * (kg ^ r7));
        f16x8 ap11 = *(const f16x8*)(myP + (16 + fr) * 64 + 8 * ((kg + 4) ^ r7));
        __builtin_amdgcn_s_setprio(1);
#pragma unroll
        for (int df = 0; df < 4; ++df) {
            const f16* vb = &sVT[df * 16 + fr][0];
            f16x8 bv0 = *(const f16x8*)(vb + kg * 8);
            f16x8 bv1 = *(const f16x8*)(vb + 32 + kg * 8);
            oacc[0][df] = MFMA16x16x32(bv0, ap00, oacc[0][df]);
            oacc[0][df] = MFMA16x16x32(bv1, ap01, oacc[0][df]);
            oacc[1][df] = MFMA16x16x32(bv0, ap10, oacc[1][df]);
            oacc[1][df] = MFMA16x16x32(bv1, ap11, oacc[1][df]);
        }
        __builtin_amdgcn_s_setprio(0);

        __syncthreads();               // all waves done reading sK/sVT
        if (more) {
            stage_write();             // regs loaded one compute-phase ago
            __syncthreads();           // new tile visible
        }
    }

    // Final l reduce across kg groups (keys partitioned by kg)
    float inv[2];
#pragma unroll
    for (int s = 0; s < 2; ++s) {
        float l = lsum[s];
        l += __shfl_xor(l, 16, 64);
        l += __shfl_xor(l, 32, 64);
        inv[s] = 1.0f / l;
    }

    // Epilogue transpose via wave-private LDS regions (stride 68 floats).
    float* const so = (wv == 0) ? (float*)&sK[0][0]
                    : (wv == 1) ? (float*)&sVT[0][0]
                    : (float*)&sPS[0][0] + (wv == 3 ? 2176 : 0);
#pragma unroll
    for (int s = 0; s < 2; ++s) {
#pragma unroll
        for (int df = 0; df < 4; ++df) {
            f32x4 v = oacc[s][df];
            v *= inv[s];
            *(f32x4*)(so + fr * 68 + df * 16 + kg * 4) = v;
        }
        int row = lane >> 2;
        int cb = (lane & 3) * 16;
        float* dst = out + ((size_t)b * SEQ + q0 + wv * 32 + s * 16 + row) * HIDDEN
                         + h * HDIM + cb;
#pragma unroll
        for (int i = 0; i < 4; ++i) {
            f32x4 v = *(const f32x4*)(so + row * 68 + cb + 4 * i);
            *(f32x4*)(dst + 4 * i) = v;
        }
    }
}

// ---------------------------------------------------------------------------
extern "C" void kernel_launch(void* const* d_in, const int* in_sizes, int n_in,
                              void* d_out, int out_size, void* d_ws, size_t ws_size,
                              hipStream_t stream) {
    const float* X      = (const float*)d_in[0];
    const float* Wq     = (const float*)d_in[1];
    const float* bq     = (const float*)d_in[2];
    const float* Wk     = (const float*)d_in[3];
    const float* bk     = (const float*)d_in[4];
    const float* Wv     = (const float*)d_in[5];
    const float* bv     = (const float*)d_in[6];
    const float* alphas = (const float*)d_in[7];
    float* out = (float*)d_out;

    const size_t nQ = (size_t)BATCH * HEADS * SEQ * HDIM;
    f16* qf  = (f16*)d_ws;
    f16* kf  = qf + nQ;
    f16* vtf = kf + nQ;
    float* biasTab = (float*)(vtf + nQ);
    f16* Xh = (f16*)(biasTab + 49152);
    f16* Wh = Xh + (size_t)8192 * 768;

    const int prep_threads = NCVT + NBIAS;
    hipLaunchKernelGGL(prep_kernel, dim3((prep_threads + 255) / 256), dim3(256), 0,
                       stream, X, Wq, Wk, Wv, alphas, Xh, Wh, biasTab);
    hipLaunchKernelGGL(qkv_kernel, dim3(1152), dim3(256), 0, stream,
                       Xh, Wh, bq, bk, bv, qf, kf, vtf);
    hipLaunchKernelGGL(attn_kernel, dim3(BATCH * HEADS * 16), dim3(256), 0, stream,
                       qf, kf, vtf, biasTab, out);
}

// Round 8
// 136.015 us; speedup vs baseline: 1.3445x; 1.3445x over previous
//
#include <hip/hip_runtime.h>
#include <hip/hip_fp16.h>

#define HIDDEN 768
#define HEADS 12
#define HDIM 64
#define SEQ 2048
#define BATCH 4
#define ORDER 5
#define LOG2E 1.44269504088896f

typedef _Float16 f16;
typedef _Float16 f16x8 __attribute__((ext_vector_type(8)));
typedef _Float16 f16x4 __attribute__((ext_vector_type(4)));
typedef float f32x4 __attribute__((ext_vector_type(4)));

#define MFMA16x16x32(A, B, C) __builtin_amdgcn_mfma_f32_16x16x32_f16(A, B, C, 0, 0, 0)

#define GLD16(gptr, lptr)                                                     \
    __builtin_amdgcn_global_load_lds(                                         \
        (const __attribute__((address_space(1))) void*)(gptr),                \
        (__attribute__((address_space(3))) void*)(lptr), 16, 0, 0)

// ---------------------------------------------------------------------------
// Kernel 1: prep. (a) convert X -> Xh f16, Wq/Wk/Wv -> Wh[2304][768] f16;
// (b) Chebyshev bias table (x LOG2E).
// ---------------------------------------------------------------------------
#define NXG (8192 * 768 / 8)
#define NWG (768 * 768 / 8)
#define NCVT (NXG + 3 * NWG)
#define NBIAS (HEADS * (2 * SEQ - 1))

__global__ __launch_bounds__(256)
void prep_kernel(const float* __restrict__ X,
                 const float* __restrict__ Wq, const float* __restrict__ Wk,
                 const float* __restrict__ Wv, const float* __restrict__ alphas,
                 f16* __restrict__ Xh, f16* __restrict__ Wh,
                 float* __restrict__ biasTab)
{
    const int tid = blockIdx.x * 256 + threadIdx.x;
    if (tid < NCVT) {
        const float* src;
        f16* dst;
        size_t off;
        if (tid < NXG)               { src = X;  dst = Xh;              off = (size_t)tid * 8; }
        else if (tid < NXG + NWG)    { src = Wq; dst = Wh;              off = (size_t)(tid - NXG) * 8; }
        else if (tid < NXG + 2*NWG)  { src = Wk; dst = Wh + 768 * 768;  off = (size_t)(tid - NXG - NWG) * 8; }
        else                         { src = Wv; dst = Wh + 2*768*768;  off = (size_t)(tid - NXG - 2*NWG) * 8; }
        float4 a = *(const float4*)(src + off);
        float4 b = *(const float4*)(src + off + 4);
        f16x8 h;
        h[0] = (f16)a.x; h[1] = (f16)a.y; h[2] = (f16)a.z; h[3] = (f16)a.w;
        h[4] = (f16)b.x; h[5] = (f16)b.y; h[6] = (f16)b.z; h[7] = (f16)b.w;
        *(f16x8*)(dst + off) = h;
    } else {
        int idx = tid - NCVT;
        if (idx >= NBIAS) return;
        const int W = 2 * SEQ - 1;
        int h = idx / W;
        int t = idx - h * W;
        float x = (float)(t - (SEQ - 1)) / (float)(SEQ - 1);
        float tp = 1.0f;
        float tc = x;
        float acc = alphas[h * (ORDER + 1) + 0] * tp + alphas[h * (ORDER + 1) + 1] * tc;
#pragma unroll
        for (int k = 2; k <= ORDER; ++k) {
            float tn = 2.0f * x * tc - tp;
            acc += alphas[h * (ORDER + 1) + k] * tn;
            tp = tc; tc = tn;
        }
        biasTab[idx] = acc * LOG2E;
    }
}

// ---------------------------------------------------------------------------
// Kernel 2: fused QKV GEMM, m97 structure (global_load_lds w16, BK=32).
// ---------------------------------------------------------------------------
__global__ __launch_bounds__(256)
void qkv_kernel(const f16* __restrict__ Xh, const f16* __restrict__ Wh,
                const float* __restrict__ bq, const float* __restrict__ bk,
                const float* __restrict__ bv,
                f16* __restrict__ qf, f16* __restrict__ kf, f16* __restrict__ vtf)
{
    const int wgid = (blockIdx.x & 7) * 144 + (blockIdx.x >> 3);
    const int tileM = wgid / 18;
    const int tileN = wgid % 18;
    const int m0 = tileM * 128;
    const int n0g = tileN * 128;
    const int w = tileN / 6;
    const int nloc0 = n0g - w * 768;
    const float* __restrict__ bias = (w == 0) ? bq : (w == 1) ? bk : bv;

    __shared__ __align__(16) f16 sA[128][32];
    __shared__ __align__(16) f16 sB[128][32];

    const int t = threadIdx.x;
    const int lane = t & 63;
    const int wv = t >> 6;
    const int wm = wv >> 1, wn = wv & 1;
    const int fr = lane & 15;
    const int kg = lane >> 4;

    const int srow = lane >> 2;
    const int scol = (lane & 3) * 8;

    f32x4 acc[4][4];
#pragma unroll
    for (int i = 0; i < 4; ++i)
#pragma unroll
        for (int j = 0; j < 4; ++j) acc[i][j] = (f32x4)(0.0f);

    const f16* gA = Xh + (size_t)(m0 + wv * 32 + srow) * 768 + scol;
    const f16* gB = Wh + (size_t)(n0g + wv * 32 + srow) * 768 + scol;
    f16* lA0 = &sA[wv * 32][0];
    f16* lA1 = &sA[wv * 32 + 16][0];
    f16* lB0 = &sB[wv * 32][0];
    f16* lB1 = &sB[wv * 32 + 16][0];

    for (int kt = 0; kt < 768; kt += 32) {
        __syncthreads();
        GLD16(gA + kt, lA0);
        GLD16(gA + kt + 16 * 768, lA1);
        GLD16(gB + kt, lB0);
        GLD16(gB + kt + 16 * 768, lB1);
        __syncthreads();

        f16x8 af[4], bf[4];
#pragma unroll
        for (int i = 0; i < 4; ++i) {
            af[i] = *(const f16x8*)&sA[wm * 64 + i * 16 + fr][kg * 8];
            bf[i] = *(const f16x8*)&sB[wn * 64 + i * 16 + fr][kg * 8];
        }
#pragma unroll
        for (int mi = 0; mi < 4; ++mi)
#pragma unroll
            for (int ni = 0; ni < 4; ++ni)
                acc[mi][ni] = MFMA16x16x32(af[mi], bf[ni], acc[mi][ni]);
    }

    const int bb = m0 >> 11;
#pragma unroll
    for (int mi = 0; mi < 4; ++mi) {
        const int s0 = (m0 & 2047) + wm * 64 + mi * 16 + kg * 4;
#pragma unroll
        for (int ni = 0; ni < 4; ++ni) {
            const int nloc = nloc0 + wn * 64 + ni * 16 + fr;
            const int hh = nloc >> 6, d = nloc & 63;
            const size_t bh = (size_t)bb * HEADS + hh;
            const float bc = bias[nloc];
            if (w == 2) {
                f16x4 pv;
#pragma unroll
                for (int r = 0; r < 4; ++r) pv[r] = (f16)(acc[mi][ni][r] + bc);
                *(f16x4*)&vtf[(bh * HDIM + d) * SEQ + s0] = pv;
            } else if (w == 0) {
#pragma unroll
                for (int r = 0; r < 4; ++r)
                    qf[(bh * SEQ + s0 + r) * HDIM + d] =
                        (f16)((acc[mi][ni][r] + bc) * (0.125f * LOG2E));
            } else {
#pragma unroll
                for (int r = 0; r < 4; ++r)
                    kf[(bh * SEQ + s0 + r) * HDIM + d] = (f16)(acc[mi][ni][r] + bc);
            }
        }
    }
}

// ---------------------------------------------------------------------------
// Kernel 3: flash attention — R3 structure (stride-72 LDS, 2 barriers/tile,
// 3 blocks/CU) + XCD-affine grid + bias-as-C-init + load-early/write-late
// staging + setprio. S^T layout, no-max softmax.
// ---------------------------------------------------------------------------
#define LDK 72

struct __align__(16) SMem {
    union {
        struct {
            f16 sK[64][LDK];
            f16 sVT[64][LDK];
        } kv;
        float sO[4][16][LDK];   // epilogue transpose, per-wave region
    } u;
    f16 sP[4][32][LDK];         // per-wave P tiles [q][key]
    float sBias[2176];          // bias*LOG2E, index u = j - q_local + 127
};

__global__ __launch_bounds__(256, 3)
void attn_kernel(const f16* __restrict__ qf, const f16* __restrict__ kf,
                 const f16* __restrict__ vtf, const float* __restrict__ biasTab,
                 float* __restrict__ out)
{
    // XCD-affine: all 16 q-tiles of one (b,h) land on one XCD.
    const int xcd = blockIdx.x & 7;
    const int ii = blockIdx.x >> 3;
    const int qt = ii & 15;
    const int bh = (ii >> 4) * 8 + xcd;     // bijective, 0..47
    const int h = bh % HEADS;
    const int b = bh / HEADS;
    const int q0 = qt * 128;

    __shared__ SMem sm;

    const int t = threadIdx.x;
    const int lane = t & 63;
    const int wv = t >> 6;
    const int fr = lane & 15;
    const int kg = lane >> 4;

    // Stage bias slice: sBias[u] = biasTab[h*4095 + u + 1920 - q0], u in [0,2175)
    {
        const float* bsrc = biasTab + (size_t)h * (2 * SEQ - 1) + 1920 - q0;
        for (int u = t; u < 2175; u += 256) sm.sBias[u] = bsrc[u];
    }

    // Q fragments in registers (0.125*LOG2E folded in by qkv kernel)
    f16x8 aq[2][2];
#pragma unroll
    for (int s = 0; s < 2; ++s)
#pragma unroll
        for (int c = 0; c < 2; ++c)
            aq[s][c] = *(const f16x8*)(qf +
                ((size_t)bh * SEQ + q0 + wv * 32 + s * 16 + fr) * HDIM + c * 32 + kg * 8);

    f32x4 oacc[2][4];
    float lsum[2] = {0.0f, 0.0f};
#pragma unroll
    for (int s = 0; s < 2; ++s)
#pragma unroll
        for (int df = 0; df < 4; ++df) oacc[s][df] = (f32x4)(0.0f);

    // staging geometry: thread t covers row t>>2, cols (t&3)*16 .. +15
    const int srow = t >> 2;
    const int scol = (t & 3) * 16;
    const f16* const gkb = kf + ((size_t)bh * SEQ + srow) * HDIM + scol;
    const f16* const gvb = vtf + ((size_t)bh * HDIM + srow) * SEQ + scol;

    f16x8 rk0, rk1, rv0, rv1;
    auto stage_load = [&](int j0) {
        rk0 = *(const f16x8*)(gkb + (size_t)j0 * HDIM);
        rk1 = *(const f16x8*)(gkb + (size_t)j0 * HDIM + 8);
        rv0 = *(const f16x8*)(gvb + j0);
        rv1 = *(const f16x8*)(gvb + j0 + 8);
    };
    auto stage_write = [&]() {
        *(f16x8*)&sm.u.kv.sK[srow][scol]      = rk0;
        *(f16x8*)&sm.u.kv.sK[srow][scol + 8]  = rk1;
        *(f16x8*)&sm.u.kv.sVT[srow][scol]     = rv0;
        *(f16x8*)&sm.u.kv.sVT[srow][scol + 8] = rv1;
    };

    // prologue: tile 0
    stage_load(0);
    stage_write();
    __syncthreads();   // tile 0 + bias visible

    for (int j0 = 0; j0 < SEQ; j0 += 64) {
        const bool more = (j0 + 64 < SEQ);
        if (more) stage_load(j0 + 64);   // HBM latency hides under compute

        // bias: element (s,ni,r): key = j0+ni*16+kg*4+r, q = wv*32+s*16+fr
        const int ub = j0 + kg * 4 - wv * 32 - fr + 127;
        float bbv[5][4];
#pragma unroll
        for (int g = 0; g < 5; ++g)
#pragma unroll
            for (int r = 0; r < 4; ++r)
                bbv[g][r] = sm.sBias[ub + (g - 1) * 16 + r];

        // T[key][q] = K Q^T, accumulator initialized with the bias
        f32x4 tt[2][4];
#pragma unroll
        for (int s = 0; s < 2; ++s)
#pragma unroll
            for (int ni = 0; ni < 4; ++ni)
#pragma unroll
                for (int r = 0; r < 4; ++r) tt[s][ni][r] = bbv[ni - s + 1][r];

        __builtin_amdgcn_s_setprio(1);
#pragma unroll
        for (int ni = 0; ni < 4; ++ni) {
            f16x8 bk0 = *(const f16x8*)&sm.u.kv.sK[ni * 16 + fr][kg * 8];
            f16x8 bk1 = *(const f16x8*)&sm.u.kv.sK[ni * 16 + fr][32 + kg * 8];
            tt[0][ni] = MFMA16x16x32(bk0, aq[0][0], tt[0][ni]);
            tt[0][ni] = MFMA16x16x32(bk1, aq[0][1], tt[0][ni]);
            tt[1][ni] = MFMA16x16x32(bk0, aq[1][0], tt[1][ni]);
            tt[1][ni] = MFMA16x16x32(bk1, aq[1][1], tt[1][ni]);
        }
        __builtin_amdgcn_s_setprio(0);

        // softmax (no max subtraction) + P -> wave-private LDS
#pragma unroll
        for (int s = 0; s < 2; ++s) {
            float ls = 0.0f;
#pragma unroll
            for (int ni = 0; ni < 4; ++ni) {
                f16x4 ph;
#pragma unroll
                for (int r = 0; r < 4; ++r) {
                    float p = __builtin_amdgcn_exp2f(tt[s][ni][r]);
                    ls += p;
                    ph[r] = (f16)p;
                }
                *(f16x4*)&sm.sP[wv][s * 16 + fr][ni * 16 + kg * 4] = ph;
            }
            lsum[s] += ls;
        }

        // PV: O^T[d][q] += MFMA(VT rows, P rows); sP wave-private, no barrier
        f16x8 ap00 = *(const f16x8*)&sm.sP[wv][fr][kg * 8];
        f16x8 ap01 = *(const f16x8*)&sm.sP[wv][fr][32 + kg * 8];
        f16x8 ap10 = *(const f16x8*)&sm.sP[wv][16 + fr][kg * 8];
        f16x8 ap11 = *(const f16x8*)&sm.sP[wv][16 + fr][32 + kg * 8];
        __builtin_amdgcn_s_setprio(1);
#pragma unroll
        for (int df = 0; df < 4; ++df) {
            f16x8 bv0 = *(const f16x8*)&sm.u.kv.sVT[df * 16 + fr][kg * 8];
            f16x8 bv1 = *(const f16x8*)&sm.u.kv.sVT[df * 16 + fr][32 + kg * 8];
            oacc[0][df] = MFMA16x16x32(bv0, ap00, oacc[0][df]);
            oacc[0][df] = MFMA16x16x32(bv1, ap01, oacc[0][df]);
            oacc[1][df] = MFMA16x16x32(bv0, ap10, oacc[1][df]);
            oacc[1][df] = MFMA16x16x32(bv1, ap11, oacc[1][df]);
        }
        __builtin_amdgcn_s_setprio(0);

        __syncthreads();               // all waves done reading sK/sVT
        if (more) {
            stage_write();             // regs landed during compute
            __syncthreads();           // next tile visible
        }
    }

    // Final l reduce across kg groups (keys partitioned by kg)
    float inv[2];
#pragma unroll
    for (int s = 0; s < 2; ++s) {
        float l = lsum[s];
        l += __shfl_xor(l, 16, 64);
        l += __shfl_xor(l, 32, 64);
        inv[s] = 1.0f / l;
    }

    __syncthreads();   // safe to reuse kv region as sO
#pragma unroll
    for (int s = 0; s < 2; ++s) {
#pragma unroll
        for (int df = 0; df < 4; ++df) {
            f32x4 v = oacc[s][df];
            v *= inv[s];
            *(f32x4*)&sm.u.sO[wv][fr][df * 16 + kg * 4] = v;
        }
        int row = lane >> 2;
        int cb = (lane & 3) * 16;
        float* dst = out + ((size_t)b * SEQ + q0 + wv * 32 + s * 16 + row) * HIDDEN
                         + h * HDIM + cb;
#pragma unroll
        for (int i = 0; i < 4; ++i) {
            f32x4 v = *(const f32x4*)&sm.u.sO[wv][row][cb + 4 * i];
            *(f32x4*)(dst + 4 * i) = v;
        }
    }
}

// ---------------------------------------------------------------------------
extern "C" void kernel_launch(void* const* d_in, const int* in_sizes, int n_in,
                              void* d_out, int out_size, void* d_ws, size_t ws_size,
                              hipStream_t stream) {
    const float* X      = (const float*)d_in[0];
    const float* Wq     = (const float*)d_in[1];
    const float* bq     = (const float*)d_in[2];
    const float* Wk     = (const float*)d_in[3];
    const float* bk     = (const float*)d_in[4];
    const float* Wv     = (const float*)d_in[5];
    const float* bv     = (const float*)d_in[6];
    const float* alphas = (const float*)d_in[7];
    float* out = (float*)d_out;

    const size_t nQ = (size_t)BATCH * HEADS * SEQ * HDIM;
    f16* qf  = (f16*)d_ws;
    f16* kf  = qf + nQ;
    f16* vtf = kf + nQ;
    float* biasTab = (float*)(vtf + nQ);
    f16* Xh = (f16*)(biasTab + 49152);
    f16* Wh = Xh + (size_t)8192 * 768;

    const int prep_threads = NCVT + NBIAS;
    hipLaunchKernelGGL(prep_kernel, dim3((prep_threads + 255) / 256), dim3(256), 0,
                       stream, X, Wq, Wk, Wv, alphas, Xh, Wh, biasTab);
    hipLaunchKernelGGL(qkv_kernel, dim3(1152), dim3(256), 0, stream,
                       Xh, Wh, bq, bk, bv, qf, kf, vtf);
    hipLaunchKernelGGL(attn_kernel, dim3(BATCH * HEADS * 16), dim3(256), 0, stream,
                       qf, kf, vtf, biasTab, out);
}

// Round 9
// 133.565 us; speedup vs baseline: 1.3692x; 1.0183x over previous
//
#include <hip/hip_runtime.h>
#include <hip/hip_fp16.h>

#define HIDDEN 768
#define HEADS 12
#define HDIM 64
#define SEQ 2048
#define BATCH 4
#define ORDER 5
#define LOG2E 1.44269504088896f

typedef _Float16 f16;
typedef _Float16 f16x8 __attribute__((ext_vector_type(8)));
typedef _Float16 f16x4 __attribute__((ext_vector_type(4)));
typedef float f32x4 __attribute__((ext_vector_type(4)));

#define MFMA16x16x32(A, B, C) __builtin_amdgcn_mfma_f32_16x16x32_f16(A, B, C, 0, 0, 0)

#define GLD16(gptr, lptr)                                                     \
    __builtin_amdgcn_global_load_lds(                                         \
        (const __attribute__((address_space(1))) void*)(gptr),                \
        (__attribute__((address_space(3))) void*)(lptr), 16, 0, 0)

// ---------------------------------------------------------------------------
// Kernel 1: prep. (a) convert X -> Xh f16, Wq/Wk/Wv -> Wh[2304][768] f16;
// (b) Chebyshev bias table (x LOG2E).
// ---------------------------------------------------------------------------
#define NXG (8192 * 768 / 8)
#define NWG (768 * 768 / 8)
#define NCVT (NXG + 3 * NWG)
#define NBIAS (HEADS * (2 * SEQ - 1))

__global__ __launch_bounds__(256)
void prep_kernel(const float* __restrict__ X,
                 const float* __restrict__ Wq, const float* __restrict__ Wk,
                 const float* __restrict__ Wv, const float* __restrict__ alphas,
                 f16* __restrict__ Xh, f16* __restrict__ Wh,
                 float* __restrict__ biasTab)
{
    const int tid = blockIdx.x * 256 + threadIdx.x;
    if (tid < NCVT) {
        const float* src;
        f16* dst;
        size_t off;
        if (tid < NXG)               { src = X;  dst = Xh;              off = (size_t)tid * 8; }
        else if (tid < NXG + NWG)    { src = Wq; dst = Wh;              off = (size_t)(tid - NXG) * 8; }
        else if (tid < NXG + 2*NWG)  { src = Wk; dst = Wh + 768 * 768;  off = (size_t)(tid - NXG - NWG) * 8; }
        else                         { src = Wv; dst = Wh + 2*768*768;  off = (size_t)(tid - NXG - 2*NWG) * 8; }
        float4 a = *(const float4*)(src + off);
        float4 b = *(const float4*)(src + off + 4);
        f16x8 h;
        h[0] = (f16)a.x; h[1] = (f16)a.y; h[2] = (f16)a.z; h[3] = (f16)a.w;
        h[4] = (f16)b.x; h[5] = (f16)b.y; h[6] = (f16)b.z; h[7] = (f16)b.w;
        *(f16x8*)(dst + off) = h;
    } else {
        int idx = tid - NCVT;
        if (idx >= NBIAS) return;
        const int W = 2 * SEQ - 1;
        int h = idx / W;
        int t = idx - h * W;
        float x = (float)(t - (SEQ - 1)) / (float)(SEQ - 1);
        float tp = 1.0f;
        float tc = x;
        float acc = alphas[h * (ORDER + 1) + 0] * tp + alphas[h * (ORDER + 1) + 1] * tc;
#pragma unroll
        for (int k = 2; k <= ORDER; ++k) {
            float tn = 2.0f * x * tc - tp;
            acc += alphas[h * (ORDER + 1) + k] * tn;
            tp = tc; tc = tn;
        }
        biasTab[idx] = acc * LOG2E;
    }
}

// ---------------------------------------------------------------------------
// Kernel 2: fused QKV GEMM, m97 structure (global_load_lds w16, BK=32).
// ---------------------------------------------------------------------------
__global__ __launch_bounds__(256)
void qkv_kernel(const f16* __restrict__ Xh, const f16* __restrict__ Wh,
                const float* __restrict__ bq, const float* __restrict__ bk,
                const float* __restrict__ bv,
                f16* __restrict__ qf, f16* __restrict__ kf, f16* __restrict__ vtf)
{
    const int wgid = (blockIdx.x & 7) * 144 + (blockIdx.x >> 3);
    const int tileM = wgid / 18;
    const int tileN = wgid % 18;
    const int m0 = tileM * 128;
    const int n0g = tileN * 128;
    const int w = tileN / 6;
    const int nloc0 = n0g - w * 768;
    const float* __restrict__ bias = (w == 0) ? bq : (w == 1) ? bk : bv;

    __shared__ __align__(16) f16 sA[128][32];
    __shared__ __align__(16) f16 sB[128][32];

    const int t = threadIdx.x;
    const int lane = t & 63;
    const int wv = t >> 6;
    const int wm = wv >> 1, wn = wv & 1;
    const int fr = lane & 15;
    const int kg = lane >> 4;

    const int srow = lane >> 2;
    const int scol = (lane & 3) * 8;

    f32x4 acc[4][4];
#pragma unroll
    for (int i = 0; i < 4; ++i)
#pragma unroll
        for (int j = 0; j < 4; ++j) acc[i][j] = (f32x4)(0.0f);

    const f16* gA = Xh + (size_t)(m0 + wv * 32 + srow) * 768 + scol;
    const f16* gB = Wh + (size_t)(n0g + wv * 32 + srow) * 768 + scol;
    f16* lA0 = &sA[wv * 32][0];
    f16* lA1 = &sA[wv * 32 + 16][0];
    f16* lB0 = &sB[wv * 32][0];
    f16* lB1 = &sB[wv * 32 + 16][0];

    for (int kt = 0; kt < 768; kt += 32) {
        __syncthreads();
        GLD16(gA + kt, lA0);
        GLD16(gA + kt + 16 * 768, lA1);
        GLD16(gB + kt, lB0);
        GLD16(gB + kt + 16 * 768, lB1);
        __syncthreads();

        f16x8 af[4], bf[4];
#pragma unroll
        for (int i = 0; i < 4; ++i) {
            af[i] = *(const f16x8*)&sA[wm * 64 + i * 16 + fr][kg * 8];
            bf[i] = *(const f16x8*)&sB[wn * 64 + i * 16 + fr][kg * 8];
        }
#pragma unroll
        for (int mi = 0; mi < 4; ++mi)
#pragma unroll
            for (int ni = 0; ni < 4; ++ni)
                acc[mi][ni] = MFMA16x16x32(af[mi], bf[ni], acc[mi][ni]);
    }

    const int bb = m0 >> 11;
#pragma unroll
    for (int mi = 0; mi < 4; ++mi) {
        const int s0 = (m0 & 2047) + wm * 64 + mi * 16 + kg * 4;
#pragma unroll
        for (int ni = 0; ni < 4; ++ni) {
            const int nloc = nloc0 + wn * 64 + ni * 16 + fr;
            const int hh = nloc >> 6, d = nloc & 63;
            const size_t bh = (size_t)bb * HEADS + hh;
            const float bc = bias[nloc];
            if (w == 2) {
                f16x4 pv;
#pragma unroll
                for (int r = 0; r < 4; ++r) pv[r] = (f16)(acc[mi][ni][r] + bc);
                *(f16x4*)&vtf[(bh * HDIM + d) * SEQ + s0] = pv;
            } else if (w == 0) {
#pragma unroll
                for (int r = 0; r < 4; ++r)
                    qf[(bh * SEQ + s0 + r) * HDIM + d] =
                        (f16)((acc[mi][ni][r] + bc) * (0.125f * LOG2E));
            } else {
#pragma unroll
                for (int r = 0; r < 4; ++r)
                    kf[(bh * SEQ + s0 + r) * HDIM + d] = (f16)(acc[mi][ni][r] + bc);
            }
        }
    }
}

// ---------------------------------------------------------------------------
// Kernel 3: flash attention — R8 structure with XOR-chunk-swizzled K/VT/P
// LDS layouts (linear stride 64 + chunk^row&7) to kill b128 bank conflicts.
// ---------------------------------------------------------------------------
struct __align__(16) SMem {
    union {
        struct {
            f16 sK[64][64];
            f16 sVT[64][64];
        } kv;                   // 16384 B
        float sO[4][16][72];    // 18432 B, epilogue transpose per-wave
    } u;
    f16 sP[4][32][64];          // per-wave P [q][key], swizzled, 16384 B
    float sBias[2176];          // 8704 B
};

__global__ __launch_bounds__(256, 3)
void attn_kernel(const f16* __restrict__ qf, const f16* __restrict__ kf,
                 const f16* __restrict__ vtf, const float* __restrict__ biasTab,
                 float* __restrict__ out)
{
    // XCD-affine: all 16 q-tiles of one (b,h) land on one XCD.
    const int xcd = blockIdx.x & 7;
    const int ii = blockIdx.x >> 3;
    const int qt = ii & 15;
    const int bh = (ii >> 4) * 8 + xcd;     // bijective, 0..47
    const int h = bh % HEADS;
    const int b = bh / HEADS;
    const int q0 = qt * 128;

    __shared__ SMem sm;

    const int t = threadIdx.x;
    const int lane = t & 63;
    const int wv = t >> 6;
    const int fr = lane & 15;
    const int kg = lane >> 4;
    const int r7 = fr & 7;

    // Stage bias slice: sBias[u] = biasTab[h*4095 + u + 1920 - q0], u in [0,2175)
    {
        const float* bsrc = biasTab + (size_t)h * (2 * SEQ - 1) + 1920 - q0;
        for (int u = t; u < 2175; u += 256) sm.sBias[u] = bsrc[u];
    }

    // Q fragments in registers (0.125*LOG2E folded in by qkv kernel)
    f16x8 aq[2][2];
#pragma unroll
    for (int s = 0; s < 2; ++s)
#pragma unroll
        for (int c = 0; c < 2; ++c)
            aq[s][c] = *(const f16x8*)(qf +
                ((size_t)bh * SEQ + q0 + wv * 32 + s * 16 + fr) * HDIM + c * 32 + kg * 8);

    f32x4 oacc[2][4];
    float lsum[2] = {0.0f, 0.0f};
#pragma unroll
    for (int s = 0; s < 2; ++s)
#pragma unroll
        for (int df = 0; df < 4; ++df) oacc[s][df] = (f32x4)(0.0f);

    // staging geometry: thread t covers row t>>2, chunks (t&3)*2 and +1
    const int srow = t >> 2;
    const int scol = (t & 3) * 16;
    const int sw0 = 8 * (((t & 3) * 2) ^ (srow & 7));      // swizzled chunk 0
    const int sw1 = 8 * (((t & 3) * 2 + 1) ^ (srow & 7));  // swizzled chunk 1
    const f16* const gkb = kf + ((size_t)bh * SEQ + srow) * HDIM + scol;
    const f16* const gvb = vtf + ((size_t)bh * HDIM + srow) * SEQ + scol;
    f16* const myP = &sm.sP[wv][0][0];

    f16x8 rk0, rk1, rv0, rv1;
    auto stage_load = [&](int j0) {
        rk0 = *(const f16x8*)(gkb + (size_t)j0 * HDIM);
        rk1 = *(const f16x8*)(gkb + (size_t)j0 * HDIM + 8);
        rv0 = *(const f16x8*)(gvb + j0);
        rv1 = *(const f16x8*)(gvb + j0 + 8);
    };
    auto stage_write = [&]() {
        *(f16x8*)&sm.u.kv.sK[srow][sw0]  = rk0;
        *(f16x8*)&sm.u.kv.sK[srow][sw1]  = rk1;
        *(f16x8*)&sm.u.kv.sVT[srow][sw0] = rv0;
        *(f16x8*)&sm.u.kv.sVT[srow][sw1] = rv1;
    };

    // prologue: tile 0
    stage_load(0);
    stage_write();
    __syncthreads();   // tile 0 + bias visible

    for (int j0 = 0; j0 < SEQ; j0 += 64) {
        const bool more = (j0 + 64 < SEQ);
        if (more) stage_load(j0 + 64);   // HBM latency hides under compute

        // bias: element (s,ni,r): key = j0+ni*16+kg*4+r, q = wv*32+s*16+fr
        const int ub = j0 + kg * 4 - wv * 32 - fr + 127;
        float bbv[5][4];
#pragma unroll
        for (int g = 0; g < 5; ++g)
#pragma unroll
            for (int r = 0; r < 4; ++r)
                bbv[g][r] = sm.sBias[ub + (g - 1) * 16 + r];

        // T[key][q] = K Q^T, accumulator initialized with the bias
        f32x4 tt[2][4];
#pragma unroll
        for (int s = 0; s < 2; ++s)
#pragma unroll
            for (int ni = 0; ni < 4; ++ni)
#pragma unroll
                for (int r = 0; r < 4; ++r) tt[s][ni][r] = bbv[ni - s + 1][r];

        __builtin_amdgcn_s_setprio(1);
#pragma unroll
        for (int ni = 0; ni < 4; ++ni) {
            const f16* kb = &sm.u.kv.sK[ni * 16 + fr][0];
            f16x8 bk0 = *(const f16x8*)(kb + 8 * (kg ^ r7));
            f16x8 bk1 = *(const f16x8*)(kb + 8 * ((kg + 4) ^ r7));
            tt[0][ni] = MFMA16x16x32(bk0, aq[0][0], tt[0][ni]);
            tt[0][ni] = MFMA16x16x32(bk1, aq[0][1], tt[0][ni]);
            tt[1][ni] = MFMA16x16x32(bk0, aq[1][0], tt[1][ni]);
            tt[1][ni] = MFMA16x16x32(bk1, aq[1][1], tt[1][ni]);
        }
        __builtin_amdgcn_s_setprio(0);

        // softmax (no max subtraction) + P -> wave-private LDS (swizzled)
#pragma unroll
        for (int s = 0; s < 2; ++s) {
            float ls = 0.0f;
#pragma unroll
            for (int ni = 0; ni < 4; ++ni) {
                f16x4 ph;
#pragma unroll
                for (int r = 0; r < 4; ++r) {
                    float p = __builtin_amdgcn_exp2f(tt[s][ni][r]);
                    ls += p;
                    ph[r] = (f16)p;
                }
                *(f16x4*)(myP + (s * 16 + fr) * 64 +
                          (((ni * 2 + (kg >> 1)) ^ r7) * 8) + (kg & 1) * 4) = ph;
            }
            lsum[s] += ls;
        }

        // PV: O^T[d][q] += MFMA(VT rows, P rows); sP wave-private, no barrier
        f16x8 ap00 = *(const f16x8*)(myP + fr * 64 + 8 * (kg ^ r7));
        f16x8 ap01 = *(const f16x8*)(myP + fr * 64 + 8 * ((kg + 4) ^ r7));
        f16x8 ap10 = *(const f16x8*)(myP + (16 + fr) * 64 + 8 * (kg ^ r7));
        f16x8 ap11 = *(const f16x8*)(myP + (16 + fr) * 64 + 8 * ((kg + 4) ^ r7));
        __builtin_amdgcn_s_setprio(1);
#pragma unroll
        for (int df = 0; df < 4; ++df) {
            const f16* vb = &sm.u.kv.sVT[df * 16 + fr][0];
            f16x8 bv0 = *(const f16x8*)(vb + 8 * (kg ^ r7));
            f16x8 bv1 = *(const f16x8*)(vb + 8 * ((kg + 4) ^ r7));
            oacc[0][df] = MFMA16x16x32(bv0, ap00, oacc[0][df]);
            oacc[0][df] = MFMA16x16x32(bv1, ap01, oacc[0][df]);
            oacc[1][df] = MFMA16x16x32(bv0, ap10, oacc[1][df]);
            oacc[1][df] = MFMA16x16x32(bv1, ap11, oacc[1][df]);
        }
        __builtin_amdgcn_s_setprio(0);

        __syncthreads();               // all waves done reading sK/sVT
        if (more) {
            stage_write();             // regs landed during compute
            __syncthreads();           // next tile visible
        }
    }

    // Final l reduce across kg groups (keys partitioned by kg)
    float inv[2];
#pragma unroll
    for (int s = 0; s < 2; ++s) {
        float l = lsum[s];
        l += __shfl_xor(l, 16, 64);
        l += __shfl_xor(l, 32, 64);
        inv[s] = 1.0f / l;
    }

    __syncthreads();   // safe to reuse kv region as sO
#pragma unroll
    for (int s = 0; s < 2; ++s) {
#pragma unroll
        for (int df = 0; df < 4; ++df) {
            f32x4 v = oacc[s][df];
            v *= inv[s];
            *(f32x4*)&sm.u.sO[wv][fr][df * 16 + kg * 4] = v;
        }
        int row = lane >> 2;
        int cb = (lane & 3) * 16;
        float* dst = out + ((size_t)b * SEQ + q0 + wv * 32 + s * 16 + row) * HIDDEN
                         + h * HDIM + cb;
#pragma unroll
        for (int i = 0; i < 4; ++i) {
            f32x4 v = *(const f32x4*)&sm.u.sO[wv][row][cb + 4 * i];
            *(f32x4*)(dst + 4 * i) = v;
        }
    }
}

// ---------------------------------------------------------------------------
extern "C" void kernel_launch(void* const* d_in, const int* in_sizes, int n_in,
                              void* d_out, int out_size, void* d_ws, size_t ws_size,
                              hipStream_t stream) {
    const float* X      = (const float*)d_in[0];
    const float* Wq     = (const float*)d_in[1];
    const float* bq     = (const float*)d_in[2];
    const float* Wk     = (const float*)d_in[3];
    const float* bk     = (const float*)d_in[4];
    const float* Wv     = (const float*)d_in[5];
    const float* bv     = (const float*)d_in[6];
    const float* alphas = (const float*)d_in[7];
    float* out = (float*)d_out;

    const size_t nQ = (size_t)BATCH * HEADS * SEQ * HDIM;
    f16* qf  = (f16*)d_ws;
    f16* kf  = qf + nQ;
    f16* vtf = kf + nQ;
    float* biasTab = (float*)(vtf + nQ);
    f16* Xh = (f16*)(biasTab + 49152);
    f16* Wh = Xh + (size_t)8192 * 768;

    const int prep_threads = NCVT + NBIAS;
    hipLaunchKernelGGL(prep_kernel, dim3((prep_threads + 255) / 256), dim3(256), 0,
                       stream, X, Wq, Wk, Wv, alphas, Xh, Wh, biasTab);
    hipLaunchKernelGGL(qkv_kernel, dim3(1152), dim3(256), 0, stream,
                       Xh, Wh, bq, bk, bv, qf, kf, vtf);
    hipLaunchKernelGGL(attn_kernel, dim3(BATCH * HEADS * 16), dim3(256), 0, stream,
                       qf, kf, vtf, biasTab, out);
}